// Round 9
// baseline (258.550 us; speedup 1.0000x reference)
//
#include <hip/hip_runtime.h>
#include <hip/hip_bf16.h>
#include <stdint.h>

// Shapes (fixed by the problem)
#define BATCH 2048
#define NHID  512
#define KMAIN 65792          // 257*256 = 1028*64  (k = i*256 + j, j<256)
#define KPAD  66112          // KMAIN + 320 = 1033*64 (tail: k-KMAIN = i, j=256 col)
#define NSTEP 1033
#define SPLITS 4             // 4 splits x 256 steps = steps [0,1024)
#define AW 320               // a_tab row width (256 vals, 1.0 at 256, zeros to 320)
#define CW 256               // c_tab row width

typedef __attribute__((ext_vector_type(8))) short short8;
typedef __attribute__((ext_vector_type(4))) short short4v;
typedef __attribute__((ext_vector_type(4))) float f32x4;

#define AS1 __attribute__((address_space(1)))
#define AS3 __attribute__((address_space(3)))

__device__ __forceinline__ unsigned short f2bf(float f) {
    union { float f; unsigned int u; } v; v.f = f;
    unsigned int r = v.u + 0x7FFFu + ((v.u >> 16) & 1u);
    return (unsigned short)(r >> 16);
}
__device__ __forceinline__ float bf2f(unsigned short u) {
    union { unsigned int i; float f; } v; v.i = ((unsigned int)u) << 16;
    return v.f;
}

// W1 source row for permuted k (or -1 for zero-pad)
__device__ __forceinline__ int w1_src_row(int k) {
    if (k < KMAIN) return (k >> 8) * 257 + (k & 255);   // i*257 + j
    int i = k - KMAIN;
    return (i < 257) ? (i * 257 + 256) : -1;             // (i, j=256) column
}

// ---------------------------------------------------------------------------
// Merged prep: W1t (permuted transpose+cvt), W2t (transpose+cvt),
// a_tab [2048][320] bf16, c_tab [2048][256] bf16.  One launch.
// ---------------------------------------------------------------------------
__global__ __launch_bounds__(256) void prep_kernel(
        const float* __restrict__ inp1, const float* __restrict__ inp2,
        const float* __restrict__ W1, const float* __restrict__ W2,
        unsigned short* __restrict__ W1t, unsigned short* __restrict__ W2t,
        unsigned short* __restrict__ a_tab, unsigned short* __restrict__ c_tab) {
    __shared__ float T[64][65];
    int b = blockIdx.x;
    int t = threadIdx.x;

    if (b < 8264 + 64) {
        const float* src; unsigned short* dst; int k0, n0, Kpad; bool perm;
        if (b < 8264) {
            int kt = b % 1033, nt = b / 1033;
            src = W1; dst = W1t; k0 = kt * 64; n0 = nt * 64; Kpad = KPAD; perm = true;
        } else {
            int bb = b - 8264;
            int kt = bb & 7, nt = bb >> 3;
            src = W2; dst = W2t; k0 = kt * 64; n0 = nt * 64; Kpad = 512; perm = false;
        }
        int nn = t & 63, kk0 = t >> 6;
#pragma unroll
        for (int it = 0; it < 16; ++it) {
            int kk = it * 4 + kk0;
            int k = k0 + kk;
            int row = perm ? w1_src_row(k) : k;
            float v = (row >= 0) ? src[(long)row * NHID + n0 + nn] : 0.f;
            T[kk][nn] = v;
        }
        __syncthreads();
#pragma unroll
        for (int it = 0; it < 2; ++it) {
            int idx = it * 256 + t;
            int nl = idx >> 3, ch = idx & 7;
            short8 o;
#pragma unroll
            for (int e = 0; e < 8; ++e) o[e] = (short)f2bf(T[ch * 8 + e][nl]);
            *reinterpret_cast<short8*>(&dst[(long)(n0 + nl) * Kpad + k0 + ch * 8]) = o;
        }
    } else {
        int r0 = (b - 8328) * 32;
        for (int idx = t; idx < 32 * (AW / 8); idx += 256) {
            int r = idx / 40, ch = idx - r * 40;
            int m = r0 + r;
            short8 o;
#pragma unroll
            for (int e = 0; e < 8; ++e) {
                int i = ch * 8 + e;
                float v = (i < 256) ? inp1[m * 256 + i] : (i == 256 ? 1.0f : 0.0f);
                o[e] = (short)f2bf(v);
            }
            *reinterpret_cast<short8*>(&a_tab[m * AW + ch * 8]) = o;
        }
        for (int idx = t; idx < 32 * (CW / 8); idx += 256) {
            int r = idx >> 5, ch = idx & 31;
            int m = r0 + r;
            short8 o;
#pragma unroll
            for (int e = 0; e < 8; ++e) o[e] = (short)f2bf(inp2[m * 256 + ch * 8 + e]);
            *reinterpret_cast<short8*>(&c_tab[m * CW + ch * 8]) = o;
        }
    }
}

// ---------------------------------------------------------------------------
// Stage a [128 rows][64 k] bf16 tile into LDS via global_load_lds (16B),
// XOR swizzle via permuted per-lane source chunk.  4 VMEM instrs per wave.
// ---------------------------------------------------------------------------
__device__ __forceinline__ void stage_tile128(const unsigned short* __restrict__ g,
        long row0, long k0, long ld, unsigned short* lds) {
    int t = threadIdx.x;
    int wave = t >> 6, lane = t & 63;
    int rl = lane >> 3;
    int ch = (lane & 7) ^ rl;
    const unsigned short* src0 = g + (row0 + wave * 8 + rl) * ld + k0 + ch * 8;
#pragma unroll
    for (int r = 0; r < 4; ++r) {
        const unsigned short* src = src0 + (long)r * 32 * ld;
        unsigned short* dst = lds + (r * 32 + wave * 8) * 64;   // wave-uniform
        __builtin_amdgcn_global_load_lds((const AS1 unsigned int*)src,
                                         (AS3 unsigned int*)dst, 16, 0, 0);
    }
}

// Fragment read: logical (rowbase+(lane&15), k = kofs + (lane>>4)*8 .. +8)
__device__ __forceinline__ short8 read_frag(const unsigned short* lds,
        int rowbase, int kofs, int lane) {
    int row = rowbase + (lane & 15);
    int chunkL = (kofs >> 3) + (lane >> 4);
    int sw = chunkL ^ (row & 7);
    return *reinterpret_cast<const short8*>(&lds[row * 64 + sw * 8]);
}

// ---------------------------------------------------------------------------
// GEMM1 via  h[m,n] = sum_i a[m,i] * P_i[m,n],
//   P_i[m,n] = sum_j c[m,j] * W1t[n, i*256+j].
// fm=4 x fn=2: wave = 64 rows x 32 cols -> each B-fragment read feeds 4
// MFMAs (LDS instrs halved vs fm=2; the per-CU LDS b128 issue rate was the
// measured wall at R8).  A-operand = raw register-cached c-chunk; P folded
// into acc per i-group with f32 a[output-row] from a transposed LDS window.
// Depth-3 pipelined B staging, counted vmcnt (never 0 in steady state).
// 4 waves side-by-side in n: block = 64 rows x 128 cols.
// grid = 32(M) * 4(N) * 4(S) = 512 blocks = 2/CU, 256 steps each.
// ---------------------------------------------------------------------------
__global__ __launch_bounds__(256, 2) void gemm1_kernel(
        const unsigned short* __restrict__ a_tab,
        const unsigned short* __restrict__ c_tab,
        const unsigned short* __restrict__ W1t, float* __restrict__ hacc) {
    __shared__ __align__(16) unsigned short B_s[3 * 128 * 64];   // 48 KB ring
    __shared__ __align__(16) unsigned short a_ldsT[64 * 64];     // 8 KB [i][row]

    int bid = (blockIdx.x & 7) * 64 + (blockIdx.x >> 3);   // XCD swizzle, 512=8*64
    int m0 = (bid & 31) * 64;
    int n0 = ((bid >> 5) & 3) * 128;
    int s  = bid >> 7;
    int st0 = s * 256;
    int stLast = st0 + 255;

    int lane = threadIdx.x & 63;
    int wv = threadIdx.x >> 6;
    int frow = lane & 15;                  // fragment row within 16
    int kq = (lane >> 4) * 8;
    int r4 = (lane >> 4) * 4;

    // ---- per-lane c-chunk cache: cc[fm][q] = c_tab[m0+fm*16+frow][kq+32q ..+8)
    short8 cc[4][8];
#pragma unroll
    for (int fm = 0; fm < 4; ++fm)
#pragma unroll
        for (int q = 0; q < 8; ++q)
            cc[fm][q] = *reinterpret_cast<const short8*>(
                &c_tab[(m0 + fm * 16 + frow) * CW + kq + q * 32]);

    // ---- transposed a-window: a_ldsT[i][row] = a_tab[m0+row][s*64+i] ----
#pragma unroll
    for (int e = 0; e < 16; ++e) {
        int idx = threadIdx.x * 16 + e;
        int i = idx >> 6, row = idx & 63;
        a_ldsT[idx] = a_tab[(m0 + row) * AW + s * 64 + i];
    }

    f32x4 acc[4][2];
#pragma unroll
    for (int a = 0; a < 4; ++a)
#pragma unroll
        for (int b = 0; b < 2; ++b) acc[a][b] = (f32x4){0.f, 0.f, 0.f, 0.f};

    // ---- prologue: stage st0, st0+1; full drain (publishes a_ldsT too) ----
    stage_tile128(W1t, n0, (long)st0 * 64, KPAD, B_s);
    stage_tile128(W1t, n0, (long)(st0 + 1) * 64, KPAD, B_s + 8192);
    __syncthreads();

    int cur = 0;
    for (int g = 0; g < 64; ++g) {         // i = s*64 + g
        f32x4 P[4][2];
#pragma unroll
        for (int a = 0; a < 4; ++a)
#pragma unroll
            for (int b = 0; b < 2; ++b) P[a][b] = (f32x4){0.f, 0.f, 0.f, 0.f};
#pragma unroll
        for (int p = 0; p < 4; ++p) {
            int st = st0 + g * 4 + p;
            if (st == stLast) asm volatile("s_waitcnt vmcnt(0)" ::: "memory");
            else              asm volatile("s_waitcnt vmcnt(4)" ::: "memory");
            __builtin_amdgcn_s_barrier();
            __builtin_amdgcn_sched_barrier(0);
            if (st + 2 <= stLast) {
                int nb = cur + 2; if (nb >= 3) nb -= 3;
                stage_tile128(W1t, n0, (long)(st + 2) * 64, KPAD, B_s + nb * 8192);
            }
            const unsigned short* bb = B_s + cur * 8192;
            __builtin_amdgcn_s_setprio(1);
#pragma unroll
            for (int kk = 0; kk < 2; ++kk) {
                short8 bF0 = read_frag(bb, wv * 32,      kk * 32, lane);
                short8 bF1 = read_frag(bb, wv * 32 + 16, kk * 32, lane);
#pragma unroll
                for (int fm = 0; fm < 4; ++fm) {
                    P[fm][0] = __builtin_amdgcn_mfma_f32_16x16x32_bf16(
                        cc[fm][2 * p + kk], bF0, P[fm][0], 0, 0, 0);
                    P[fm][1] = __builtin_amdgcn_mfma_f32_16x16x32_bf16(
                        cc[fm][2 * p + kk], bF1, P[fm][1], 0, 0, 0);
                }
            }
            __builtin_amdgcn_s_setprio(0);
            cur = (cur == 2) ? 0 : cur + 1;
        }
        // ---- fold i-group into acc with a[OUTPUT row, i] (f32) ----
#pragma unroll
        for (int fm = 0; fm < 4; ++fm) {
            short4v a4 = *reinterpret_cast<const short4v*>(&a_ldsT[g * 64 + fm * 16 + r4]);
#pragma unroll
            for (int r = 0; r < 4; ++r) {
                float av = bf2f((unsigned short)a4[r]);
                acc[fm][0][r] += av * P[fm][0][r];
                acc[fm][1][r] += av * P[fm][1][r];
            }
        }
    }

    // ---- split 3 appends the 9 leftover steps (sloppy loop, hidden) ----
    if (s == 3) {
#pragma unroll
        for (int p = 0; p < 4; ++p) {       // st = 1024+p: i=256 row, a==1
            __syncthreads();
            stage_tile128(W1t, n0, (long)(1024 + p) * 64, KPAD, B_s);
            __syncthreads();
#pragma unroll
            for (int kk = 0; kk < 2; ++kk) {
                short8 bF0 = read_frag(B_s, wv * 32,      kk * 32, lane);
                short8 bF1 = read_frag(B_s, wv * 32 + 16, kk * 32, lane);
#pragma unroll
                for (int fm = 0; fm < 4; ++fm) {
                    acc[fm][0] = __builtin_amdgcn_mfma_f32_16x16x32_bf16(
                        cc[fm][2 * p + kk], bF0, acc[fm][0], 0, 0, 0);
                    acc[fm][1] = __builtin_amdgcn_mfma_f32_16x16x32_bf16(
                        cc[fm][2 * p + kk], bF1, acc[fm][1], 0, 0, 0);
                }
            }
        }
        for (int st = 1028; st < 1033; ++st) {   // tail: fusion col = a(m,i)
            __syncthreads();
            stage_tile128(W1t, n0, (long)st * 64, KPAD, B_s);
            int koff = (st - 1028) * 64 + kq;
            short8 tA[4][2];
#pragma unroll
            for (int fm = 0; fm < 4; ++fm)
#pragma unroll
                for (int kk = 0; kk < 2; ++kk)
                    tA[fm][kk] = *reinterpret_cast<const short8*>(
                        &a_tab[(m0 + fm * 16 + frow) * AW + koff + kk * 32]);
            __syncthreads();
#pragma unroll
            for (int kk = 0; kk < 2; ++kk) {
                short8 bF0 = read_frag(B_s, wv * 32,      kk * 32, lane);
                short8 bF1 = read_frag(B_s, wv * 32 + 16, kk * 32, lane);
#pragma unroll
                for (int fm = 0; fm < 4; ++fm) {
                    acc[fm][0] = __builtin_amdgcn_mfma_f32_16x16x32_bf16(
                        tA[fm][kk], bF0, acc[fm][0], 0, 0, 0);
                    acc[fm][1] = __builtin_amdgcn_mfma_f32_16x16x32_bf16(
                        tA[fm][kk], bF1, acc[fm][1], 0, 0, 0);
                }
            }
        }
    }

    // ---- epilogue: atomic split-K accumulate into f32 hacc ----
#pragma unroll
    for (int fm = 0; fm < 4; ++fm)
#pragma unroll
        for (int fn = 0; fn < 2; ++fn)
#pragma unroll
            for (int r = 0; r < 4; ++r) {
                int row = m0 + fm * 16 + r4 + r;
                int col = n0 + wv * 32 + fn * 16 + frow;
                atomicAdd(&hacc[row * NHID + col], acc[fm][fn][r]);
            }
}

// h = bf16(relu(hacc + b1))
__global__ __launch_bounds__(256) void bias_relu_h_kernel(
        const float* __restrict__ hacc, const float* __restrict__ b1,
        unsigned short* __restrict__ h) {
    int idx = blockIdx.x * 256 + threadIdx.x;
    f32x4 v = ((const f32x4*)hacc)[idx];
    int col = (idx & 127) << 2;
    f32x4 bb = *(const f32x4*)(b1 + col);
    short4v o;
#pragma unroll
    for (int e = 0; e < 4; ++e) {
        float x = v[e] + bb[e];
        x = fmaxf(x, 0.f);
        o[e] = (short)f2bf(x);
    }
    ((short4v*)h)[idx] = o;
}

// ---------------------------------------------------------------------------
// GEMM2: out = relu(h @ W2 + b2).  M=2048,N=512,K=512.  grid 16x4.
// ---------------------------------------------------------------------------
__global__ __launch_bounds__(256) void gemm2_kernel(
        const unsigned short* __restrict__ h, const unsigned short* __restrict__ W2t,
        const float* __restrict__ b2, float* __restrict__ out) {
    __shared__ unsigned short A_s[128 * 64];
    __shared__ unsigned short B_s[128 * 64];
    int m0 = (blockIdx.x >> 2) * 128;
    int n0 = (blockIdx.x & 3) * 128;
    int lane = threadIdx.x & 63;
    int wv = threadIdx.x >> 6;
    int wm = (wv >> 1) * 64;
    int wn = (wv & 1) * 64;

    f32x4 acc[4][4];
#pragma unroll
    for (int a = 0; a < 4; ++a)
#pragma unroll
        for (int b = 0; b < 4; ++b) acc[a][b] = (f32x4){0.f, 0.f, 0.f, 0.f};

    for (int st = 0; st < 8; ++st) {
        int kbase = st * 64;
        __syncthreads();
        stage_tile128(h,   m0, kbase, NHID, A_s);
        stage_tile128(W2t, n0, kbase, NHID, B_s);
        __syncthreads();
#pragma unroll
        for (int kk = 0; kk < 2; ++kk) {
            short8 aF[4], bF[4];
#pragma unroll
            for (int fm = 0; fm < 4; ++fm) aF[fm] = read_frag(A_s, wm + fm * 16, kk * 32, lane);
#pragma unroll
            for (int fn = 0; fn < 4; ++fn) bF[fn] = read_frag(B_s, wn + fn * 16, kk * 32, lane);
#pragma unroll
            for (int fm = 0; fm < 4; ++fm)
#pragma unroll
                for (int fn = 0; fn < 4; ++fn)
                    acc[fm][fn] = __builtin_amdgcn_mfma_f32_16x16x32_bf16(
                        aF[fm], bF[fn], acc[fm][fn], 0, 0, 0);
        }
    }
    int cl = lane & 15;
    int r4 = (lane >> 4) * 4;
#pragma unroll
    for (int fm = 0; fm < 4; ++fm)
#pragma unroll
        for (int fn = 0; fn < 4; ++fn)
#pragma unroll
            for (int r = 0; r < 4; ++r) {
                int row = m0 + wm + fm * 16 + r4 + r;
                int col = n0 + wn + fn * 16 + cl;
                float x = acc[fm][fn][r] + b2[col];
                out[row * NHID + col] = fmaxf(x, 0.f);
            }
}

extern "C" void kernel_launch(void* const* d_in, const int* in_sizes, int n_in,
                              void* d_out, int out_size, void* d_ws, size_t ws_size,
                              hipStream_t stream) {
    const float* inp1 = (const float*)d_in[0];
    const float* inp2 = (const float*)d_in[1];
    const float* W1   = (const float*)d_in[2];
    const float* b1   = (const float*)d_in[3];
    const float* W2   = (const float*)d_in[4];
    const float* b2   = (const float*)d_in[5];
    float* out = (float*)d_out;

    // workspace layout (~72.5 MB)
    size_t off = 0;
    auto alloc = [&](size_t bytes) {
        void* p = (char*)d_ws + off;
        off += (bytes + 255) & ~(size_t)255;
        return p;
    };
    unsigned short* W1t   = (unsigned short*)alloc((size_t)NHID * KPAD * 2);
    unsigned short* W2t   = (unsigned short*)alloc((size_t)NHID * NHID * 2);
    unsigned short* h     = (unsigned short*)alloc((size_t)BATCH * NHID * 2);
    unsigned short* a_tab = (unsigned short*)alloc((size_t)BATCH * AW * 2);
    unsigned short* c_tab = (unsigned short*)alloc((size_t)BATCH * CW * 2);
    (void)ws_size; (void)in_sizes; (void)n_in; (void)out_size;

    // d_out doubles as the f32 split-K accumulator for h_pre
    hipMemsetAsync(d_out, 0, (size_t)BATCH * NHID * 4, stream);

    prep_kernel<<<8264 + 64 + 64, 256, 0, stream>>>(inp1, inp2, W1, W2,
                                                    W1t, W2t, a_tab, c_tab);

    gemm1_kernel<<<32 * 4 * SPLITS, 256, 0, stream>>>(a_tab, c_tab, W1t, (float*)d_out);
    bias_relu_h_kernel<<<(BATCH * NHID / 4) / 256, 256, 0, stream>>>((const float*)d_out, b1, h);
    gemm2_kernel<<<64, 256, 0, stream>>>(h, W2t, b2, out);
}

// Round 10
// 181.988 us; speedup vs baseline: 1.4207x; 1.4207x over previous
//
#include <hip/hip_runtime.h>
#include <hip/hip_bf16.h>
#include <stdint.h>

// Shapes (fixed by the problem)
#define BATCH 2048
#define NHID  512
#define KMAIN 65792          // 257*256  (k = i*256 + j, j<256; i=0..256)
#define KPAD  66112          // 1033*64  (tail 5 steps: j=256 column, A=a(m,i))
#define NSTEP_ALL 1033
#define AW 320               // a_tab row width (257 vals: a[256]=1.0; zeros to 320)
#define CW 256               // c_tab row width

typedef __attribute__((ext_vector_type(8))) short short8;
typedef __attribute__((ext_vector_type(4))) short short4v;
typedef __attribute__((ext_vector_type(4))) float f32x4;

#define AS1 __attribute__((address_space(1)))
#define AS3 __attribute__((address_space(3)))

__device__ __forceinline__ unsigned short f2bf(float f) {
    union { float f; unsigned int u; } v; v.f = f;
    unsigned int r = v.u + 0x7FFFu + ((v.u >> 16) & 1u);
    return (unsigned short)(r >> 16);
}
__device__ __forceinline__ float bf2f(unsigned short u) {
    union { unsigned int i; float f; } v; v.i = ((unsigned int)u) << 16;
    return v.f;
}
__device__ __forceinline__ f32x4 MFMA16(short8 a, short8 b, f32x4 c) {
    return __builtin_amdgcn_mfma_f32_16x16x32_bf16(a, b, c, 0, 0, 0);
}

// W1 source row for permuted k (or -1 for zero-pad)
__device__ __forceinline__ int w1_src_row(int k) {
    if (k < KMAIN) return (k >> 8) * 257 + (k & 255);   // i*257 + j
    int i = k - KMAIN;
    return (i < 257) ? (i * 257 + 256) : -1;             // (i, j=256) column
}

// ---------------------------------------------------------------------------
// Merged prep: W1f (FRAGMENT-MAJOR permuted W1), W2t (row-major transpose),
// a_tab [2048][320] bf16, c_tab [2048][256] bf16.  One launch.
// W1f layout: chunk(n16, st, kk, lane) at ((n16*1033+st)*2+kk)*512 + lane*8,
// elems e: value = W1perm[st*64 + kk*32 + (lane>>4)*8 + e][n16*16 + (lane&15)].
// A wave's whole per-step B-operand = 4 coalesced dwordx4 loads.
// ---------------------------------------------------------------------------
__global__ __launch_bounds__(256) void prep_kernel(
        const float* __restrict__ inp1, const float* __restrict__ inp2,
        const float* __restrict__ W1, const float* __restrict__ W2,
        unsigned short* __restrict__ W1f, unsigned short* __restrict__ W2t,
        unsigned short* __restrict__ a_tab, unsigned short* __restrict__ c_tab) {
    __shared__ float T[64][65];
    int b = blockIdx.x;
    int t = threadIdx.x;

    if (b < 8264) {
        // ---- W1f tile: 64 k x 64 n ----
        int kt = b % 1033, nt = b / 1033;
        int k0 = kt * 64, n0 = nt * 64;
        int nn = t & 63, kk0 = t >> 6;
#pragma unroll
        for (int it = 0; it < 16; ++it) {
            int kk = it * 4 + kk0;
            int row = w1_src_row(k0 + kk);
            T[kk][nn] = (row >= 0) ? W1[(long)row * NHID + n0 + nn] : 0.f;
        }
        __syncthreads();
#pragma unroll
        for (int it = 0; it < 2; ++it) {
            int id = it * 256 + t;
            int n16l = id >> 7;            // 0..3
            int kk   = (id >> 6) & 1;
            int lw   = id & 63;
            short8 o;
#pragma unroll
            for (int e = 0; e < 8; ++e)
                o[e] = (short)f2bf(T[kk * 32 + (lw >> 4) * 8 + e][n16l * 16 + (lw & 15)]);
            size_t off = ((size_t)(((n0 >> 4) + n16l) * NSTEP_ALL + kt) * 2 + kk) * 512
                         + (size_t)lw * 8;
            *reinterpret_cast<short8*>(&W1f[off]) = o;
        }
    } else if (b < 8264 + 64) {
        // ---- W2t: plain transpose+cvt (row-major, gemm2's LDS path) ----
        int bb = b - 8264;
        int kt = bb & 7, nt = bb >> 3;
        int k0 = kt * 64, n0 = nt * 64;
        int nn = t & 63, kk0 = t >> 6;
#pragma unroll
        for (int it = 0; it < 16; ++it) {
            int kk = it * 4 + kk0;
            T[kk][nn] = W2[(long)(k0 + kk) * NHID + n0 + nn];
        }
        __syncthreads();
#pragma unroll
        for (int it = 0; it < 2; ++it) {
            int idx = it * 256 + t;
            int nl = idx >> 3, ch = idx & 7;
            short8 o;
#pragma unroll
            for (int e = 0; e < 8; ++e) o[e] = (short)f2bf(T[ch * 8 + e][nl]);
            *reinterpret_cast<short8*>(&W2t[(long)(n0 + nl) * NHID + k0 + ch * 8]) = o;
        }
    } else {
        int r0 = (b - 8328) * 32;
        for (int idx = t; idx < 32 * (AW / 8); idx += 256) {
            int r = idx / 40, ch = idx - r * 40;
            int m = r0 + r;
            short8 o;
#pragma unroll
            for (int e = 0; e < 8; ++e) {
                int i = ch * 8 + e;
                float v = (i < 256) ? inp1[m * 256 + i] : (i == 256 ? 1.0f : 0.0f);
                o[e] = (short)f2bf(v);
            }
            *reinterpret_cast<short8*>(&a_tab[m * AW + ch * 8]) = o;
        }
        for (int idx = t; idx < 32 * (CW / 8); idx += 256) {
            int r = idx >> 5, ch = idx & 31;
            int m = r0 + r;
            short8 o;
#pragma unroll
            for (int e = 0; e < 8; ++e) o[e] = (short)f2bf(inp2[m * 256 + ch * 8 + e]);
            *reinterpret_cast<short8*>(&c_tab[m * CW + ch * 8]) = o;
        }
    }
}

// ---------------------------------------------------------------------------
// Stage helper + swizzled fragment read (used by gemm2 only now)
// ---------------------------------------------------------------------------
__device__ __forceinline__ void stage_tile128(const unsigned short* __restrict__ g,
        long row0, long k0, long ld, unsigned short* lds) {
    int t = threadIdx.x;
    int wave = t >> 6, lane = t & 63;
    int rl = lane >> 3;
    int ch = (lane & 7) ^ rl;
    const unsigned short* src0 = g + (row0 + wave * 8 + rl) * ld + k0 + ch * 8;
#pragma unroll
    for (int r = 0; r < 4; ++r) {
        const unsigned short* src = src0 + (long)r * 32 * ld;
        unsigned short* dst = lds + (r * 32 + wave * 8) * 64;
        __builtin_amdgcn_global_load_lds((const AS1 unsigned int*)src,
                                         (AS3 unsigned int*)dst, 16, 0, 0);
    }
}
__device__ __forceinline__ short8 read_frag(const unsigned short* lds,
        int rowbase, int kofs, int lane) {
    int row = rowbase + (lane & 15);
    int chunkL = (kofs >> 3) + (lane >> 4);
    int sw = chunkL ^ (row & 7);
    return *reinterpret_cast<const short8*>(&lds[row * 64 + sw * 8]);
}

// ---------------------------------------------------------------------------
// GEMM1, BARRIER-FREE:  h[m,n] = sum_i a[m,i] * P_i[m,n],
//   P_i[m,n] = sum_j c[m,j] * W1t[n, i*256+j].
// Each wave owns 64 rows x 32 cols, fully independent: B fragments read
// straight from fragment-major W1f (4 coalesced dwordx4/step, register
// double-buffered, no LDS, no barriers, no vmcnt choreography).  A-operand
// = raw register-cached c-chunks; fold per i-group with f32 a from an LDS
// window (filled once; single init barrier).
// grid: bid = mb*64 + (nt + 16*s): all 8 mb-blocks of a (nt,s) group land on
// the same XCD (bid%8 equal) -> shared 1MB W1f window stays L2-resident.
// 512 blocks x 256 thr = 2 blocks/CU, 8 waves/CU.
// ---------------------------------------------------------------------------
__global__ __launch_bounds__(256, 2) void gemm1_kernel(
        const unsigned short* __restrict__ a_tab,
        const unsigned short* __restrict__ c_tab,
        const unsigned short* __restrict__ W1f, float* __restrict__ hacc) {
    __shared__ __align__(16) unsigned short a_win[65 * 256];   // [i][row] 33 KB

    int mb = blockIdx.x >> 6;          // 0..7: 256-row slab
    int g8 = blockIdx.x & 63;
    int nt = g8 & 15;                  // 32-col slice
    int s  = g8 >> 4;                  // split 0..3
    int st0 = s * 256;
    int ngroups = (s == 3) ? 65 : 64;  // s=3 also covers i=256 (a==1) group

    int lane = threadIdx.x & 63;
    int wv   = threadIdx.x >> 6;
    int rowbase = mb * 256 + wv * 64;
    int frow = lane & 15;
    int kq = (lane >> 4) * 8;
    int r4 = (lane >> 4) * 4;
    int n16a = nt * 2, n16b = nt * 2 + 1;

    // per-lane c-chunk cache: cc[fm][q] = c_tab[rowbase+fm*16+frow][kq+32q ..+8)
    short8 cc[4][8];
#pragma unroll
    for (int fm = 0; fm < 4; ++fm)
#pragma unroll
        for (int q = 0; q < 8; ++q)
            cc[fm][q] = *reinterpret_cast<const short8*>(
                &c_tab[(size_t)(rowbase + fm * 16 + frow) * CW + kq + q * 32]);

    // a-window: a_win[i][row] = a_tab[mb*256+row][s*64+i], i in [0,65)
    {
        const unsigned short* src = a_tab + (size_t)(mb * 256 + threadIdx.x) * AW + s * 64;
        for (int i = 0; i < 65; ++i) a_win[i * 256 + threadIdx.x] = src[i];
    }
    __syncthreads();                   // the ONLY barrier

    f32x4 acc[4][2];
#pragma unroll
    for (int a = 0; a < 4; ++a)
#pragma unroll
        for (int b2 = 0; b2 < 2; ++b2) acc[a][b2] = (f32x4){0.f, 0.f, 0.f, 0.f};

    short8 bufE0, bufE1, bufE2, bufE3, bufO0, bufO1, bufO2, bufO3;

#define LOADSTEP(st, D) do { \
    const unsigned short* _p0 = W1f + ((size_t)(n16a * NSTEP_ALL + (st))) * 1024 + lane * 8; \
    const unsigned short* _p1 = W1f + ((size_t)(n16b * NSTEP_ALL + (st))) * 1024 + lane * 8; \
    D##0 = *reinterpret_cast<const short8*>(_p0); \
    D##1 = *reinterpret_cast<const short8*>(_p0 + 512); \
    D##2 = *reinterpret_cast<const short8*>(_p1); \
    D##3 = *reinterpret_cast<const short8*>(_p1 + 512); \
} while (0)
// chunks: D0 = fn0/kk0, D1 = fn0/kk1, D2 = fn1/kk0, D3 = fn1/kk1
#define MFSTEP(B, p) do { \
    _Pragma("unroll") \
    for (int fm = 0; fm < 4; ++fm) { \
        P[fm][0] = MFMA16(cc[fm][2 * (p)],     B##0, P[fm][0]); \
        P[fm][1] = MFMA16(cc[fm][2 * (p)],     B##2, P[fm][1]); \
        P[fm][0] = MFMA16(cc[fm][2 * (p) + 1], B##1, P[fm][0]); \
        P[fm][1] = MFMA16(cc[fm][2 * (p) + 1], B##3, P[fm][1]); \
    } \
} while (0)

    LOADSTEP(st0, bufE);               // prologue

    for (int g = 0; g < ngroups; ++g) {
        int stg = st0 + g * 4;
        f32x4 P[4][2];
#pragma unroll
        for (int a = 0; a < 4; ++a)
#pragma unroll
            for (int b2 = 0; b2 < 2; ++b2) P[a][b2] = (f32x4){0.f, 0.f, 0.f, 0.f};

        LOADSTEP(stg + 1, bufO);  MFSTEP(bufE, 0);
        LOADSTEP(stg + 2, bufE);  MFSTEP(bufO, 1);
        LOADSTEP(stg + 3, bufO);  MFSTEP(bufE, 2);
        LOADSTEP(stg + 4, bufE);  MFSTEP(bufO, 3);   // max st0+260=1028 < 1033 ok

        // fold i-group with a[OUTPUT row, i] in f32 (C/D rows are r4-based)
#pragma unroll
        for (int fm = 0; fm < 4; ++fm) {
            short4v a4 = *reinterpret_cast<const short4v*>(
                &a_win[g * 256 + wv * 64 + fm * 16 + r4]);
#pragma unroll
            for (int r = 0; r < 4; ++r) {
                float av = bf2f((unsigned short)a4[r]);
                acc[fm][0][r] += av * P[fm][0][r];
                acc[fm][1][r] += av * P[fm][1][r];
            }
        }
    }

    // tail (s==3): steps 1028..1032, fusion col = a(m,i); bufE holds 1028
    if (s == 3) {
#define TAILMF(B, p) do { \
    _Pragma("unroll") \
    for (int fm = 0; fm < 4; ++fm) { \
        const unsigned short* _ar = a_tab + (size_t)(rowbase + fm * 16 + frow) * AW + (p) * 64 + kq; \
        short8 t0 = *reinterpret_cast<const short8*>(_ar); \
        short8 t1 = *reinterpret_cast<const short8*>(_ar + 32); \
        acc[fm][0] = MFMA16(t0, B##0, acc[fm][0]); \
        acc[fm][1] = MFMA16(t0, B##2, acc[fm][1]); \
        acc[fm][0] = MFMA16(t1, B##1, acc[fm][0]); \
        acc[fm][1] = MFMA16(t1, B##3, acc[fm][1]); \
    } \
} while (0)
        LOADSTEP(1029, bufO);  TAILMF(bufE, 0);
        LOADSTEP(1030, bufE);  TAILMF(bufO, 1);
        LOADSTEP(1031, bufO);  TAILMF(bufE, 2);
        LOADSTEP(1032, bufE);  TAILMF(bufO, 3);
        TAILMF(bufE, 4);
    }

    // epilogue: atomic split-K accumulate into f32 hacc
#pragma unroll
    for (int fm = 0; fm < 4; ++fm)
#pragma unroll
        for (int fn = 0; fn < 2; ++fn)
#pragma unroll
            for (int r = 0; r < 4; ++r) {
                int row = rowbase + fm * 16 + r4 + r;
                int col = nt * 32 + fn * 16 + frow;
                atomicAdd(&hacc[row * NHID + col], acc[fm][fn][r]);
            }
}

// h = bf16(relu(hacc + b1))
__global__ __launch_bounds__(256) void bias_relu_h_kernel(
        const float* __restrict__ hacc, const float* __restrict__ b1,
        unsigned short* __restrict__ h) {
    int idx = blockIdx.x * 256 + threadIdx.x;
    f32x4 v = ((const f32x4*)hacc)[idx];
    int col = (idx & 127) << 2;
    f32x4 bb = *(const f32x4*)(b1 + col);
    short4v o;
#pragma unroll
    for (int e = 0; e < 4; ++e) {
        float x = v[e] + bb[e];
        x = fmaxf(x, 0.f);
        o[e] = (short)f2bf(x);
    }
    ((short4v*)h)[idx] = o;
}

// ---------------------------------------------------------------------------
// GEMM2: out = relu(h @ W2 + b2).  M=2048,N=512,K=512.  grid 16x4.
// ---------------------------------------------------------------------------
__global__ __launch_bounds__(256) void gemm2_kernel(
        const unsigned short* __restrict__ h, const unsigned short* __restrict__ W2t,
        const float* __restrict__ b2, float* __restrict__ out) {
    __shared__ unsigned short A_s[128 * 64];
    __shared__ unsigned short B_s[128 * 64];
    int m0 = (blockIdx.x >> 2) * 128;
    int n0 = (blockIdx.x & 3) * 128;
    int lane = threadIdx.x & 63;
    int wv = threadIdx.x >> 6;
    int wm = (wv >> 1) * 64;
    int wn = (wv & 1) * 64;

    f32x4 acc[4][4];
#pragma unroll
    for (int a = 0; a < 4; ++a)
#pragma unroll
        for (int b = 0; b < 4; ++b) acc[a][b] = (f32x4){0.f, 0.f, 0.f, 0.f};

    for (int st = 0; st < 8; ++st) {
        int kbase = st * 64;
        __syncthreads();
        stage_tile128(h,   m0, kbase, NHID, A_s);
        stage_tile128(W2t, n0, kbase, NHID, B_s);
        __syncthreads();
#pragma unroll
        for (int kk = 0; kk < 2; ++kk) {
            short8 aF[4], bF[4];
#pragma unroll
            for (int fm = 0; fm < 4; ++fm) aF[fm] = read_frag(A_s, wm + fm * 16, kk * 32, lane);
#pragma unroll
            for (int fn = 0; fn < 4; ++fn) bF[fn] = read_frag(B_s, wn + fn * 16, kk * 32, lane);
#pragma unroll
            for (int fm = 0; fm < 4; ++fm)
#pragma unroll
                for (int fn = 0; fn < 4; ++fn)
                    acc[fm][fn] = __builtin_amdgcn_mfma_f32_16x16x32_bf16(
                        aF[fm], bF[fn], acc[fm][fn], 0, 0, 0);
        }
    }
    int cl = lane & 15;
    int r4 = (lane >> 4) * 4;
#pragma unroll
    for (int fm = 0; fm < 4; ++fm)
#pragma unroll
        for (int fn = 0; fn < 4; ++fn)
#pragma unroll
            for (int r = 0; r < 4; ++r) {
                int row = m0 + wm + fm * 16 + r4 + r;
                int col = n0 + wn + fn * 16 + cl;
                float x = acc[fm][fn][r] + b2[col];
                out[row * NHID + col] = fmaxf(x, 0.f);
            }
}

extern "C" void kernel_launch(void* const* d_in, const int* in_sizes, int n_in,
                              void* d_out, int out_size, void* d_ws, size_t ws_size,
                              hipStream_t stream) {
    const float* inp1 = (const float*)d_in[0];
    const float* inp2 = (const float*)d_in[1];
    const float* W1   = (const float*)d_in[2];
    const float* b1   = (const float*)d_in[3];
    const float* W2   = (const float*)d_in[4];
    const float* b2   = (const float*)d_in[5];
    float* out = (float*)d_out;

    // workspace layout (~72.5 MB)
    size_t off = 0;
    auto alloc = [&](size_t bytes) {
        void* p = (char*)d_ws + off;
        off += (bytes + 255) & ~(size_t)255;
        return p;
    };
    unsigned short* W1f   = (unsigned short*)alloc((size_t)32 * NSTEP_ALL * 1024 * 2);
    unsigned short* W2t   = (unsigned short*)alloc((size_t)NHID * NHID * 2);
    unsigned short* h     = (unsigned short*)alloc((size_t)BATCH * NHID * 2);
    unsigned short* a_tab = (unsigned short*)alloc((size_t)BATCH * AW * 2);
    unsigned short* c_tab = (unsigned short*)alloc((size_t)BATCH * CW * 2);
    (void)ws_size; (void)in_sizes; (void)n_in; (void)out_size;

    // d_out doubles as the f32 split-K accumulator for h_pre
    hipMemsetAsync(d_out, 0, (size_t)BATCH * NHID * 4, stream);

    prep_kernel<<<8264 + 64 + 64, 256, 0, stream>>>(inp1, inp2, W1, W2,
                                                    W1f, W2t, a_tab, c_tab);

    gemm1_kernel<<<512, 256, 0, stream>>>(a_tab, c_tab, W1f, (float*)d_out);
    bias_relu_h_kernel<<<(BATCH * NHID / 4) / 256, 256, 0, stream>>>((const float*)d_out, b1, h);
    gemm2_kernel<<<64, 256, 0, stream>>>(h, W2t, b2, out);
}